// Round 2
// baseline (2596.834 us; speedup 1.0000x reference)
//
#include <hip/hip_runtime.h>

#define N_NODES 100000
#define N_EDGES 3200000
#define N_GRAPHS 64
#define M_PAD   100096   // 782 * 128 — all node-feature buffers padded to this
#define CAP     128      // padded per-node edge capacity (Poisson(32): P(deg>=128) ~ 1e-43)

typedef unsigned short u16;
typedef __bf16 bf16x8 __attribute__((ext_vector_type(8)));
typedef float f32x4 __attribute__((ext_vector_type(4)));
typedef unsigned int u32x4 __attribute__((ext_vector_type(4)));
typedef __attribute__((address_space(3))) unsigned int lds_u32;
typedef __attribute__((address_space(1))) unsigned int glb_u32;

__device__ inline u16 f2bf(float f) {
  unsigned u = __float_as_uint(f);
  unsigned r = (u + 0x7fffu + ((u >> 16) & 1u)) >> 16;
  return (u16)r;
}
__device__ inline float bf2f(u16 h) {
  return __uint_as_float(((unsigned)h) << 16);
}

// ---------------------------------------------------------------- merged graph build:
// out-degree histogram + padded dst-major edge table in ONE atomic pass.
// cur[] ends as the in-degree. 4 edges per thread (grid-strided, coalesced) -> 4
// independent atomic chains in flight per thread (was 1: latency-bound).
// colp stores are non-temporal: write-once random scatter, keep it out of LLC.
#define E4 (N_EDGES / 4)
__global__ void k_build(const int* __restrict__ src, const int* __restrict__ dst,
                        int* __restrict__ odeg, int* __restrict__ cur,
                        int* __restrict__ colp) {
  int t = blockIdx.x * blockDim.x + threadIdx.x;
  if (t >= E4) return;
  int s[4], d[4], pos[4];
  #pragma unroll
  for (int q = 0; q < 4; ++q) {
    int e = t + q * E4;
    s[q] = src[e];
    d[q] = dst[e];
  }
  #pragma unroll
  for (int q = 0; q < 4; ++q) atomicAdd(&odeg[s[q]], 1);   // fire-and-forget
  #pragma unroll
  for (int q = 0; q < 4; ++q) pos[q] = atomicAdd(&cur[d[q]], 1);
  #pragma unroll
  for (int q = 0; q < 4; ++q)
    if (pos[q] < CAP)
      __builtin_nontemporal_store(s[q], &colp[(size_t)d[q] * CAP + pos[q]]);
}

// ---------------------------------------------------------------- degree -> rsqrt norms
__global__ void k_rsqrt(const int* __restrict__ odeg, const int* __restrict__ ideg,
                        float* __restrict__ a, float* __restrict__ bI) {
  int v = blockIdx.x * blockDim.x + threadIdx.x;
  if (v < N_NODES) {
    a[v]  = rsqrtf(fmaxf((float)odeg[v], 1.0f));
    bI[v] = rsqrtf(fmaxf((float)ideg[v], 1.0f));
  }
}

// ---------------------------------------------------------------- h (fp32) -> bf16, row-scaled by ascl
__global__ void k_prep(const float* __restrict__ x, const float* __restrict__ ascl,
                       u16* __restrict__ y) {
  int i = blockIdx.x * blockDim.x + threadIdx.x;   // one float4 per thread
  if (i >= N_NODES * 128) return;                   // 128 float4 per 512-row
  int row = i >> 7;
  float s = ascl[row];
  float4 v = ((const float4*)x)[i];
  uint2 o;
  o.x = (unsigned)f2bf(v.x * s) | ((unsigned)f2bf(v.y * s) << 16);
  o.y = (unsigned)f2bf(v.z * s) | ((unsigned)f2bf(v.w * s) << 16);
  ((uint2*)y)[i] = o;
}

// ---------------------------------------------------------------- W[K][N] fp32 -> Wt[N][K] bf16
__global__ void k_wt(const float* __restrict__ W, u16* __restrict__ Wt, int fi, int fo) {
  int idx = blockIdx.x * blockDim.x + threadIdx.x;
  if (idx >= fi * fo) return;
  int n = idx / fi, k = idx % fi;
  Wt[idx] = f2bf(W[(size_t)k * fo + n]);
}

// ---------------------------------------------------------------- bf16 MFMA GEMM (m97-style staging)
// C[M_PAD,N] = A[M_PAD,K] @ Wt[N,K]^T
// flags: bit0 relu(x+bias[col]); bit1 x*=rowscale[row]
template<int BM, int BN, int WM, int WN>
__global__ __launch_bounds__(256) void k_mfma(
    const u16* __restrict__ A, const u16* __restrict__ Wt,
    const float* __restrict__ bias, const float* __restrict__ rowscale,
    u16* __restrict__ C, int N, int K, int flags)
{
  constexpr int BK = 32;
  constexpr int WX = BN / WN;
  constexpr int WY = BM / WM;
  static_assert(WX * WY == 4, "4 waves");
  constexpr int TM = WM / 16;
  constexpr int TN = WN / 16;
  constexpr int CA = BM / 16;   // 1KB chunks per A tile
  constexpr int CB = BN / 16;

  __shared__ __align__(1024) u16 As[BM * BK];
  __shared__ __align__(1024) u16 Bs[BN * BK];

  const int tid  = threadIdx.x;
  const int wave = tid >> 6;
  const int lane = tid & 63;
  const int wx = wave % WX;
  const int wy = wave / WX;
  const int bm = blockIdx.y * BM;
  const int bn = blockIdx.x * BN;

  const int lm = lane & 15;
  const int lc = lane >> 4;        // logical k-chunk for fragments (0..3)

  const int srA = (lane >> 2);     // row within 16-row chunk
  const int spA = lane & 3;        // physical chunk slot
  f32x4 acc[TM][TN] = {};

  for (int k0 = 0; k0 < K; k0 += BK) {
    #pragma unroll
    for (int q0 = 0; q0 < CA; q0 += 4) {
      int q = q0 + wave;
      if (q < CA) {
        int rl = q * 16 + srA;
        int c  = (spA - (rl >> 1)) & 3;
        const u16* g = A + (size_t)(bm + rl) * K + k0 + c * 8;
        __builtin_amdgcn_global_load_lds((const glb_u32*)g, (lds_u32*)(As + q * 512), 16, 0, 0);
      }
    }
    #pragma unroll
    for (int q0 = 0; q0 < CB; q0 += 4) {
      int q = q0 + wave;
      if (q < CB) {
        int rl = q * 16 + srA;
        int c  = (spA - (rl >> 1)) & 3;
        const u16* g = Wt + (size_t)(bn + rl) * K + k0 + c * 8;
        __builtin_amdgcn_global_load_lds((const glb_u32*)g, (lds_u32*)(Bs + q * 512), 16, 0, 0);
      }
    }
    __syncthreads();

    bf16x8 af[TM], bfr[TN];
    #pragma unroll
    for (int i = 0; i < TM; ++i) {
      int rl = wy * WM + i * 16 + lm;
      int p = (lc + (rl >> 1)) & 3;
      af[i] = *(const bf16x8*)(As + rl * 32 + p * 8);
    }
    #pragma unroll
    for (int j = 0; j < TN; ++j) {
      int rl = wx * WN + j * 16 + lm;
      int p = (lc + (rl >> 1)) & 3;
      bfr[j] = *(const bf16x8*)(Bs + rl * 32 + p * 8);
    }
    #pragma unroll
    for (int i = 0; i < TM; ++i)
      #pragma unroll
      for (int j = 0; j < TN; ++j)
        acc[i][j] = __builtin_amdgcn_mfma_f32_16x16x32_bf16(af[i], bfr[j], acc[i][j], 0, 0, 0);
    __syncthreads();
  }

  const bool do_br = flags & 1;
  const bool do_rs = flags & 2;
  #pragma unroll
  for (int i = 0; i < TM; ++i) {
    #pragma unroll
    for (int j = 0; j < TN; ++j) {
      int col = bn + wx * WN + j * 16 + lm;
      float bv = do_br ? bias[col] : 0.f;
      #pragma unroll
      for (int r = 0; r < 4; ++r) {
        int row = bm + wy * WM + i * 16 + lc * 4 + r;
        float v = acc[i][j][r];
        if (do_rs) v *= rowscale[row];
        if (do_br) v = fmaxf(v + bv, 0.f);
        C[(size_t)row * N + col] = f2bf(v);
      }
    }
  }
}

// ---------------------------------------------------------------- padded-CSR pull SpMM
// ONE NODE PER WAVE, edge-parallel lane groups: TPR = D/8 lanes cover one edge's
// row slice (16B each), EPW = 64/TPR edges in flight across the wave. UN edge-
// chunks are kept in flight PER LANE so every layer has >=8 outstanding 16B
// gathers (round-1 counters: VALUBusy 22%, HBM 46% -> latency-bound at 4 deep).
// node is wave-uniform -> readfirstlane so index/deg/scale loads go scalar
// (s_load_dwordx8 grabs 8 edge indices at once for D=512).
// Output is a write-once stream -> nontemporal store (protect LLC for gathers).
template<int D>
__global__ __launch_bounds__(256) void k_spmm(
    const int* __restrict__ deg, const int* __restrict__ colp,
    const u16* __restrict__ X, const float* __restrict__ dscale,
    const float* __restrict__ bias, u16* __restrict__ Y, int relu_bias)
{
  constexpr int TPR = D / 8;       // lanes per edge (16B of row each)
  constexpr int EPW = 64 / TPR;    // edges in flight per wave (lane-parallel)
  constexpr int UN  = (EPW >= 8) ? 1 : (8 / EPW);  // per-lane depth -> >=8 in flight
  const int lane = threadIdx.x & 63;
  const int node = __builtin_amdgcn_readfirstlane(blockIdx.x * 4 + (threadIdx.x >> 6));
  const int g = lane / TPR;        // edge slot within wave
  const int c = (lane % TPR) * 8;  // col base
  const int* cl = colp + (size_t)node * CAP;
  int e = deg[node];
  e = e < CAP ? e : CAP;
  float acc[8] = {};
  int j = 0;
  for (; j + UN * EPW <= e; j += UN * EPW) {
    int u[UN];
    #pragma unroll
    for (int t = 0; t < UN; ++t) u[t] = cl[j + g + t * EPW];
    u32x4 v[UN];
    #pragma unroll
    for (int t = 0; t < UN; ++t) v[t] = *(const u32x4*)(X + (size_t)u[t] * D + c);
    #pragma unroll
    for (int t = 0; t < UN; ++t) {
      #pragma unroll
      for (int q = 0; q < 4; ++q) {
        acc[2*q]   += __uint_as_float(v[t][q] << 16);
        acc[2*q+1] += __uint_as_float(v[t][q] & 0xffff0000u);
      }
    }
  }
  for (; j < e; j += EPW) {
    if (j + g < e) {
      int u = cl[j + g];
      u32x4 v = *(const u32x4*)(X + (size_t)u * D + c);
      #pragma unroll
      for (int q = 0; q < 4; ++q) {
        acc[2*q]   += __uint_as_float(v[q] << 16);
        acc[2*q+1] += __uint_as_float(v[q] & 0xffff0000u);
      }
    }
  }
  if constexpr (EPW > 1) {
    #pragma unroll
    for (int off = TPR; off < 64; off <<= 1) {
      #pragma unroll
      for (int q = 0; q < 8; ++q) acc[q] += __shfl_xor(acc[q], off);
    }
  }
  if (lane < TPR) {
    float dv = dscale[node];
    #pragma unroll
    for (int q = 0; q < 8; ++q) acc[q] *= dv;
    if (relu_bias) {
      #pragma unroll
      for (int q = 0; q < 8; ++q) acc[q] = fmaxf(acc[q] + bias[c + q], 0.f);
    }
    u32x4 o;
    o[0] = (unsigned)f2bf(acc[0]) | ((unsigned)f2bf(acc[1]) << 16);
    o[1] = (unsigned)f2bf(acc[2]) | ((unsigned)f2bf(acc[3]) << 16);
    o[2] = (unsigned)f2bf(acc[4]) | ((unsigned)f2bf(acc[5]) << 16);
    o[3] = (unsigned)f2bf(acc[6]) | ((unsigned)f2bf(acc[7]) << 16);
    __builtin_nontemporal_store(o, (u32x4*)(Y + (size_t)node * D + c));
  }
}

// ---------------------------------------------------------------- graph mean-pool partials
__global__ __launch_bounds__(256) void k_pool(const u16* __restrict__ h6,
                                              const int* __restrict__ gid,
                                              float* __restrict__ sums,
                                              float* __restrict__ cnts)
{
  __shared__ float acc[N_GRAPHS * 32];
  __shared__ float cnt[N_GRAPHS];
  int t = threadIdx.x;
  for (int k = t; k < N_GRAPHS * 32; k += 256) acc[k] = 0.f;
  if (t < N_GRAPHS) cnt[t] = 0.f;
  __syncthreads();
  int base = blockIdx.x * 256;
  int c = t & 31;
  int nl = t >> 5;
  for (int p = 0; p < 32; ++p) {
    int node = base + p * 8 + nl;
    if (node < N_NODES) {
      int g = gid[node];
      atomicAdd(&acc[g * 32 + c], bf2f(h6[(size_t)node * 32 + c]));
      if (c == 0) atomicAdd(&cnt[g], 1.0f);
    }
  }
  __syncthreads();
  for (int k = t; k < N_GRAPHS * 32; k += 256)
    if (acc[k] != 0.f) atomicAdd(&sums[k], acc[k]);
  if (t < N_GRAPHS && cnt[t] != 0.f) atomicAdd(&cnts[t], cnt[t]);
}

// ---------------------------------------------------------------- finalize
__global__ void k_final(const float* __restrict__ sums, const float* __restrict__ cnts,
                        const float* __restrict__ Wc, const float* __restrict__ bc,
                        float* __restrict__ out)
{
  int t = threadIdx.x;
  if (t >= N_GRAPHS * 10) return;
  int g = t / 10, cls = t % 10;
  float inv = 1.0f / fmaxf(cnts[g], 1.0f);
  float v = bc[cls];
  #pragma unroll
  for (int k = 0; k < 32; ++k)
    v += sums[g * 32 + k] * inv * Wc[k * 10 + cls];
  out[t] = v;
}

// ----------------------------------------------------------------
extern "C" void kernel_launch(void* const* d_in, const int* in_sizes, int n_in,
                              void* d_out, int out_size, void* d_ws, size_t ws_size,
                              hipStream_t stream)
{
  const float* h   = (const float*)d_in[0];
  const int*   src = (const int*)d_in[1];
  const int*   dst = (const int*)d_in[2];
  const int*   gid = (const int*)d_in[3];
  const float* W[6]; const float* b[6];
  for (int i = 0; i < 6; ++i) { W[i] = (const float*)d_in[4 + 2 * i]; b[i] = (const float*)d_in[5 + 2 * i]; }
  const float* Wc = (const float*)d_in[16];
  const float* bc = (const float*)d_in[17];
  float* out = (float*)d_out;

  const int FI[6] = {512, 1024, 512, 256, 128, 64};
  const int FO[6] = {1024, 512, 256, 128, 64, 32};

  char* p = (char*)d_ws;
  auto take = [&](size_t bytes) -> void* {
    void* r = (void*)p;
    p += (bytes + 255) & ~(size_t)255;
    return r;
  };
  u16* hb   = (u16*)take((size_t)M_PAD * 512 * 2);   // 102.5 MB
  u16* bufA = (u16*)take((size_t)M_PAD * 512 * 2);   // 102.5 MB
  u16* bufB = (u16*)take((size_t)M_PAD * 1024 * 2);  // 205 MB
  u16* Wt[6];
  for (int i = 0; i < 6; ++i) Wt[i] = (u16*)take((size_t)FI[i] * FO[i] * 2);
  int*   colp = (int*)take((size_t)N_NODES * CAP * 4);  // 51.2 MB padded edge table
  int*   odeg = (int*)take((size_t)N_NODES * 4);
  int*   cur  = (int*)take((size_t)N_NODES * 4);        // ends as in-degree
  float* ascl = (float*)take((size_t)M_PAD * 4);
  float* bscl = (float*)take((size_t)N_NODES * 4);
  float* psum = (float*)take((size_t)N_GRAPHS * 32 * 4);
  float* pcnt = (float*)take((size_t)N_GRAPHS * 4);
  if ((size_t)((char*)p - (char*)d_ws) > ws_size) return;

  // odeg and cur are adjacent: one memset covers both
  hipMemsetAsync(odeg, 0, (size_t)N_NODES * 4 * 2 + 256, stream);
  hipMemsetAsync(psum, 0, (size_t)N_GRAPHS * 32 * 4, stream);
  hipMemsetAsync(pcnt, 0, (size_t)N_GRAPHS * 4, stream);

  // ---- graph structure: single merged atomic pass, 4 edges/thread ----
  k_build<<<(E4 + 255) / 256, 256, 0, stream>>>(src, dst, odeg, cur, colp);
  k_rsqrt<<<(N_NODES + 255) / 256, 256, 0, stream>>>(odeg, cur, ascl, bscl);

  // ---- dtype prep (h pre-scaled by ascl) ----
  k_prep<<<(N_NODES * 128 + 255) / 256, 256, 0, stream>>>(h, ascl, hb);
  for (int i = 0; i < 6; ++i)
    k_wt<<<(FI[i] * FO[i] + 255) / 256, 256, 0, stream>>>(W[i], Wt[i], FI[i], FO[i]);

  const int GY = M_PAD / 128;   // 782
  const int GS = N_NODES / 4;   // 25000 — one node per wave, 4 waves/block

  // L1 (512->1024): agg first (pre-scaled input), then W + bias + relu
  k_spmm<512><<<GS, 256, 0, stream>>>(cur, colp, hb, bscl, nullptr, bufA, 0);
  k_mfma<128,128,64,64><<<dim3(8, GY), 256, 0, stream>>>(bufA, Wt[0], b[0], nullptr, bufB, 1024, 512, 1);

  // L2 (1024->512): W first (rowscaled), then agg + bias + relu
  k_mfma<128,128,64,64><<<dim3(4, GY), 256, 0, stream>>>(bufB, Wt[1], nullptr, ascl, bufA, 512, 1024, 2);
  k_spmm<512><<<GS, 256, 0, stream>>>(cur, colp, bufA, bscl, b[1], hb, 1);

  // L3 (512->256)
  k_mfma<128,128,64,64><<<dim3(2, GY), 256, 0, stream>>>(hb, Wt[2], nullptr, ascl, bufA, 256, 512, 2);
  k_spmm<256><<<GS, 256, 0, stream>>>(cur, colp, bufA, bscl, b[2], hb, 1);

  // L4 (256->128)
  k_mfma<128,128,64,64><<<dim3(1, GY), 256, 0, stream>>>(hb, Wt[3], nullptr, ascl, bufA, 128, 256, 2);
  k_spmm<128><<<GS, 256, 0, stream>>>(cur, colp, bufA, bscl, b[3], hb, 1);

  // L5 (128->64)
  k_mfma<128,64,64,32><<<dim3(1, GY), 256, 0, stream>>>(hb, Wt[4], nullptr, ascl, bufA, 64, 128, 2);
  k_spmm<64><<<GS, 256, 0, stream>>>(cur, colp, bufA, bscl, b[4], hb, 1);

  // L6 (64->32)
  k_mfma<128,32,64,16><<<dim3(1, GY), 256, 0, stream>>>(hb, Wt[5], nullptr, ascl, bufA, 32, 64, 2);
  k_spmm<32><<<GS, 256, 0, stream>>>(cur, colp, bufA, bscl, b[5], hb, 1);

  // mean-pool + classifier
  k_pool<<<(N_NODES + 255) / 256, 256, 0, stream>>>(hb, gid, psum, pcnt);
  k_final<<<1, 640, 0, stream>>>(psum, pcnt, Wc, bc, out);
}

// Round 3
// 2541.108 us; speedup vs baseline: 1.0219x; 1.0219x over previous
//
#include <hip/hip_runtime.h>

#define N_NODES 100000
#define N_EDGES 3200000
#define N_GRAPHS 64
#define M_PAD   100096   // 782 * 128 — all node-feature buffers padded to this
#define CAP     128      // padded per-node edge capacity (Poisson(32): P(deg>=128) ~ 1e-43)

typedef unsigned short u16;
typedef __bf16 bf16x8 __attribute__((ext_vector_type(8)));
typedef float f32x4 __attribute__((ext_vector_type(4)));
typedef unsigned int u32x4 __attribute__((ext_vector_type(4)));
typedef __attribute__((address_space(3))) unsigned int lds_u32;
typedef __attribute__((address_space(1))) unsigned int glb_u32;

__device__ inline u16 f2bf(float f) {
  unsigned u = __float_as_uint(f);
  unsigned r = (u + 0x7fffu + ((u >> 16) & 1u)) >> 16;
  return (u16)r;
}
__device__ inline float bf2f(u16 h) {
  return __uint_as_float(((unsigned)h) << 16);
}

// ---------------------------------------------------------------- merged graph build:
// out-degree histogram + padded dst-major edge table in ONE atomic pass.
// cur[] ends as the in-degree. 4 edges per thread; atomic-throughput-bound
// (~20G atomics/s device-wide), so depth/width changes are neutral — kept simple.
#define E4 (N_EDGES / 4)
__global__ void k_build(const int* __restrict__ src, const int* __restrict__ dst,
                        int* __restrict__ odeg, int* __restrict__ cur,
                        int* __restrict__ colp) {
  int t = blockIdx.x * blockDim.x + threadIdx.x;
  if (t >= E4) return;
  int s[4], d[4], pos[4];
  #pragma unroll
  for (int q = 0; q < 4; ++q) {
    int e = t + q * E4;
    s[q] = src[e];
    d[q] = dst[e];
  }
  #pragma unroll
  for (int q = 0; q < 4; ++q) atomicAdd(&odeg[s[q]], 1);   // fire-and-forget
  #pragma unroll
  for (int q = 0; q < 4; ++q) pos[q] = atomicAdd(&cur[d[q]], 1);
  #pragma unroll
  for (int q = 0; q < 4; ++q)
    if (pos[q] < CAP)
      __builtin_nontemporal_store(s[q], &colp[(size_t)d[q] * CAP + pos[q]]);
}

// ---------------------------------------------------------------- degree -> rsqrt norms
__global__ void k_rsqrt(const int* __restrict__ odeg, const int* __restrict__ ideg,
                        float* __restrict__ a, float* __restrict__ bI) {
  int v = blockIdx.x * blockDim.x + threadIdx.x;
  if (v < N_NODES) {
    a[v]  = rsqrtf(fmaxf((float)odeg[v], 1.0f));
    bI[v] = rsqrtf(fmaxf((float)ideg[v], 1.0f));
  }
}

// ---------------------------------------------------------------- h (fp32) -> bf16, row-scaled by ascl
__global__ void k_prep(const float* __restrict__ x, const float* __restrict__ ascl,
                       u16* __restrict__ y) {
  int i = blockIdx.x * blockDim.x + threadIdx.x;   // one float4 per thread
  if (i >= N_NODES * 128) return;                   // 128 float4 per 512-row
  int row = i >> 7;
  float s = ascl[row];
  float4 v = ((const float4*)x)[i];
  uint2 o;
  o.x = (unsigned)f2bf(v.x * s) | ((unsigned)f2bf(v.y * s) << 16);
  o.y = (unsigned)f2bf(v.z * s) | ((unsigned)f2bf(v.w * s) << 16);
  ((uint2*)y)[i] = o;
}

// ---------------------------------------------------------------- W[K][N] fp32 -> Wt[N][K] bf16
__global__ void k_wt(const float* __restrict__ W, u16* __restrict__ Wt, int fi, int fo) {
  int idx = blockIdx.x * blockDim.x + threadIdx.x;
  if (idx >= fi * fo) return;
  int n = idx / fi, k = idx % fi;
  Wt[idx] = f2bf(W[(size_t)k * fo + n]);
}

// ---------------------------------------------------------------- bf16 MFMA GEMM (m97-style staging)
// C[M_PAD,N] = A[M_PAD,K] @ Wt[N,K]^T
// flags: bit0 relu(x+bias[col]); bit1 x*=rowscale[row]
// 1-D grid with bijective XCD-chunk swizzle: HW round-robins blocks across the
// 8 XCDs, so with a plain 2D grid the (N/BN) same-A-panel blocks land on
// DIFFERENT XCDs -> each private L2 imports the whole A panel (8x fetch, the
// hidden ~285us/dispatch on L1/L2). Remap so each XCD owns a contiguous slab
// of nbid (= contiguous by panels, all bx) -> panel window ~1.5MB, L2-resident.
template<int BM, int BN, int WM, int WN>
__global__ __launch_bounds__(256) void k_mfma(
    const u16* __restrict__ A, const u16* __restrict__ Wt,
    const float* __restrict__ bias, const float* __restrict__ rowscale,
    u16* __restrict__ C, int N, int K, int flags)
{
  constexpr int BK = 32;
  constexpr int WX = BN / WN;
  constexpr int WY = BM / WM;
  static_assert(WX * WY == 4, "4 waves");
  constexpr int TM = WM / 16;
  constexpr int TN = WN / 16;
  constexpr int CA = BM / 16;   // 1KB chunks per A tile
  constexpr int CB = BN / 16;

  __shared__ __align__(1024) u16 As[BM * BK];
  __shared__ __align__(1024) u16 Bs[BN * BK];

  // ---- bijective XCD-chunked block swizzle (m204 variant; works for any G) ----
  const int G   = gridDim.x;
  const int lin = blockIdx.x;
  const int xcd = lin & 7, pp = lin >> 3;
  const int q8  = G >> 3,  r8 = G & 7;
  const int nbid = (xcd < r8 ? xcd * (q8 + 1) : r8 * (q8 + 1) + (xcd - r8) * q8) + pp;
  const int gx = N / BN;
  const int bm = (nbid / gx) * BM;
  const int bn = (nbid % gx) * BN;

  const int tid  = threadIdx.x;
  const int wave = tid >> 6;
  const int lane = tid & 63;
  const int wx = wave % WX;
  const int wy = wave / WX;

  const int lm = lane & 15;
  const int lc = lane >> 4;        // logical k-chunk for fragments (0..3)

  const int srA = (lane >> 2);     // row within 16-row chunk
  const int spA = lane & 3;        // physical chunk slot
  f32x4 acc[TM][TN] = {};

  for (int k0 = 0; k0 < K; k0 += BK) {
    #pragma unroll
    for (int q0 = 0; q0 < CA; q0 += 4) {
      int q = q0 + wave;
      if (q < CA) {
        int rl = q * 16 + srA;
        int c  = (spA - (rl >> 1)) & 3;
        const u16* g = A + (size_t)(bm + rl) * K + k0 + c * 8;
        __builtin_amdgcn_global_load_lds((const glb_u32*)g, (lds_u32*)(As + q * 512), 16, 0, 0);
      }
    }
    #pragma unroll
    for (int q0 = 0; q0 < CB; q0 += 4) {
      int q = q0 + wave;
      if (q < CB) {
        int rl = q * 16 + srA;
        int c  = (spA - (rl >> 1)) & 3;
        const u16* g = Wt + (size_t)(bn + rl) * K + k0 + c * 8;
        __builtin_amdgcn_global_load_lds((const glb_u32*)g, (lds_u32*)(Bs + q * 512), 16, 0, 0);
      }
    }
    __syncthreads();

    bf16x8 af[TM], bfr[TN];
    #pragma unroll
    for (int i = 0; i < TM; ++i) {
      int rl = wy * WM + i * 16 + lm;
      int p = (lc + (rl >> 1)) & 3;
      af[i] = *(const bf16x8*)(As + rl * 32 + p * 8);
    }
    #pragma unroll
    for (int j = 0; j < TN; ++j) {
      int rl = wx * WN + j * 16 + lm;
      int p = (lc + (rl >> 1)) & 3;
      bfr[j] = *(const bf16x8*)(Bs + rl * 32 + p * 8);
    }
    #pragma unroll
    for (int i = 0; i < TM; ++i)
      #pragma unroll
      for (int j = 0; j < TN; ++j)
        acc[i][j] = __builtin_amdgcn_mfma_f32_16x16x32_bf16(af[i], bfr[j], acc[i][j], 0, 0, 0);
    __syncthreads();
  }

  const bool do_br = flags & 1;
  const bool do_rs = flags & 2;
  #pragma unroll
  for (int i = 0; i < TM; ++i) {
    #pragma unroll
    for (int j = 0; j < TN; ++j) {
      int col = bn + wx * WN + j * 16 + lm;
      float bv = do_br ? bias[col] : 0.f;
      #pragma unroll
      for (int r = 0; r < 4; ++r) {
        int row = bm + wy * WM + i * 16 + lc * 4 + r;
        float v = acc[i][j][r];
        if (do_rs) v *= rowscale[row];
        if (do_br) v = fmaxf(v + bv, 0.f);
        C[(size_t)row * N + col] = f2bf(v);
      }
    }
  }
}

// ---------------------------------------------------------------- padded-CSR pull SpMM
// ONE NODE PER WAVE, edge-parallel lane groups: TPR = D/8 lanes cover one edge's
// row slice (16B each), EPW = 64/TPR edges in flight. 4-deep unroll (round-2's
// 8-deep regressed: VGPR 28->40, occ 76->52%, same 3.6TB/s service rate ->
// the limit is random-line service, not MLP). Zero intra-wave divergence.
// Output is a write-once stream -> nontemporal store (protect LLC for gathers).
template<int D>
__global__ __launch_bounds__(256) void k_spmm(
    const int* __restrict__ deg, const int* __restrict__ colp,
    const u16* __restrict__ X, const float* __restrict__ dscale,
    const float* __restrict__ bias, u16* __restrict__ Y, int relu_bias)
{
  constexpr int TPR = D / 8;       // lanes per edge (16B of row each)
  constexpr int EPW = 64 / TPR;    // edges in flight per wave
  const int lane = threadIdx.x & 63;
  const int node = blockIdx.x * 4 + (threadIdx.x >> 6);   // 4 waves = 4 nodes/block
  const int g = lane / TPR;        // edge slot within wave
  const int c = (lane % TPR) * 8;  // col base
  const int* cl = colp + (size_t)node * CAP;
  int e = deg[node];
  e = e < CAP ? e : CAP;
  float acc[8] = {};
  int j = 0;
  for (; j + 4 * EPW <= e; j += 4 * EPW) {
    int u0 = cl[j + g];
    int u1 = cl[j + g + EPW];
    int u2 = cl[j + g + 2 * EPW];
    int u3 = cl[j + g + 3 * EPW];
    u32x4 v0 = *(const u32x4*)(X + (size_t)u0 * D + c);
    u32x4 v1 = *(const u32x4*)(X + (size_t)u1 * D + c);
    u32x4 v2 = *(const u32x4*)(X + (size_t)u2 * D + c);
    u32x4 v3 = *(const u32x4*)(X + (size_t)u3 * D + c);
    #pragma unroll
    for (int q = 0; q < 4; ++q) {
      acc[2*q]   += __uint_as_float(v0[q] << 16);
      acc[2*q+1] += __uint_as_float(v0[q] & 0xffff0000u);
      acc[2*q]   += __uint_as_float(v1[q] << 16);
      acc[2*q+1] += __uint_as_float(v1[q] & 0xffff0000u);
      acc[2*q]   += __uint_as_float(v2[q] << 16);
      acc[2*q+1] += __uint_as_float(v2[q] & 0xffff0000u);
      acc[2*q]   += __uint_as_float(v3[q] << 16);
      acc[2*q+1] += __uint_as_float(v3[q] & 0xffff0000u);
    }
  }
  for (; j < e; j += EPW) {
    if (j + g < e) {
      int u = cl[j + g];
      u32x4 v = *(const u32x4*)(X + (size_t)u * D + c);
      #pragma unroll
      for (int q = 0; q < 4; ++q) {
        acc[2*q]   += __uint_as_float(v[q] << 16);
        acc[2*q+1] += __uint_as_float(v[q] & 0xffff0000u);
      }
    }
  }
  if constexpr (EPW > 1) {
    #pragma unroll
    for (int off = TPR; off < 64; off <<= 1) {
      #pragma unroll
      for (int q = 0; q < 8; ++q) acc[q] += __shfl_xor(acc[q], off);
    }
  }
  if (lane < TPR) {
    float dv = dscale[node];
    #pragma unroll
    for (int q = 0; q < 8; ++q) acc[q] *= dv;
    if (relu_bias) {
      #pragma unroll
      for (int q = 0; q < 8; ++q) acc[q] = fmaxf(acc[q] + bias[c + q], 0.f);
    }
    u32x4 o;
    o[0] = (unsigned)f2bf(acc[0]) | ((unsigned)f2bf(acc[1]) << 16);
    o[1] = (unsigned)f2bf(acc[2]) | ((unsigned)f2bf(acc[3]) << 16);
    o[2] = (unsigned)f2bf(acc[4]) | ((unsigned)f2bf(acc[5]) << 16);
    o[3] = (unsigned)f2bf(acc[6]) | ((unsigned)f2bf(acc[7]) << 16);
    __builtin_nontemporal_store(o, (u32x4*)(Y + (size_t)node * D + c));
  }
}

// ---------------------------------------------------------------- graph mean-pool partials
__global__ __launch_bounds__(256) void k_pool(const u16* __restrict__ h6,
                                              const int* __restrict__ gid,
                                              float* __restrict__ sums,
                                              float* __restrict__ cnts)
{
  __shared__ float acc[N_GRAPHS * 32];
  __shared__ float cnt[N_GRAPHS];
  int t = threadIdx.x;
  for (int k = t; k < N_GRAPHS * 32; k += 256) acc[k] = 0.f;
  if (t < N_GRAPHS) cnt[t] = 0.f;
  __syncthreads();
  int base = blockIdx.x * 256;
  int c = t & 31;
  int nl = t >> 5;
  for (int p = 0; p < 32; ++p) {
    int node = base + p * 8 + nl;
    if (node < N_NODES) {
      int g = gid[node];
      atomicAdd(&acc[g * 32 + c], bf2f(h6[(size_t)node * 32 + c]));
      if (c == 0) atomicAdd(&cnt[g], 1.0f);
    }
  }
  __syncthreads();
  for (int k = t; k < N_GRAPHS * 32; k += 256)
    if (acc[k] != 0.f) atomicAdd(&sums[k], acc[k]);
  if (t < N_GRAPHS && cnt[t] != 0.f) atomicAdd(&cnts[t], cnt[t]);
}

// ---------------------------------------------------------------- finalize
__global__ void k_final(const float* __restrict__ sums, const float* __restrict__ cnts,
                        const float* __restrict__ Wc, const float* __restrict__ bc,
                        float* __restrict__ out)
{
  int t = threadIdx.x;
  if (t >= N_GRAPHS * 10) return;
  int g = t / 10, cls = t % 10;
  float inv = 1.0f / fmaxf(cnts[g], 1.0f);
  float v = bc[cls];
  #pragma unroll
  for (int k = 0; k < 32; ++k)
    v += sums[g * 32 + k] * inv * Wc[k * 10 + cls];
  out[t] = v;
}

// ----------------------------------------------------------------
extern "C" void kernel_launch(void* const* d_in, const int* in_sizes, int n_in,
                              void* d_out, int out_size, void* d_ws, size_t ws_size,
                              hipStream_t stream)
{
  const float* h   = (const float*)d_in[0];
  const int*   src = (const int*)d_in[1];
  const int*   dst = (const int*)d_in[2];
  const int*   gid = (const int*)d_in[3];
  const float* W[6]; const float* b[6];
  for (int i = 0; i < 6; ++i) { W[i] = (const float*)d_in[4 + 2 * i]; b[i] = (const float*)d_in[5 + 2 * i]; }
  const float* Wc = (const float*)d_in[16];
  const float* bc = (const float*)d_in[17];
  float* out = (float*)d_out;

  const int FI[6] = {512, 1024, 512, 256, 128, 64};
  const int FO[6] = {1024, 512, 256, 128, 64, 32};

  char* p = (char*)d_ws;
  auto take = [&](size_t bytes) -> void* {
    void* r = (void*)p;
    p += (bytes + 255) & ~(size_t)255;
    return r;
  };
  u16* hb   = (u16*)take((size_t)M_PAD * 512 * 2);   // 102.5 MB
  u16* bufA = (u16*)take((size_t)M_PAD * 512 * 2);   // 102.5 MB
  u16* bufB = (u16*)take((size_t)M_PAD * 1024 * 2);  // 205 MB
  u16* Wt[6];
  for (int i = 0; i < 6; ++i) Wt[i] = (u16*)take((size_t)FI[i] * FO[i] * 2);
  int*   colp = (int*)take((size_t)N_NODES * CAP * 4);  // 51.2 MB padded edge table
  int*   odeg = (int*)take((size_t)N_NODES * 4);
  int*   cur  = (int*)take((size_t)N_NODES * 4);        // ends as in-degree
  float* ascl = (float*)take((size_t)M_PAD * 4);
  float* bscl = (float*)take((size_t)N_NODES * 4);
  float* psum = (float*)take((size_t)N_GRAPHS * 32 * 4);
  float* pcnt = (float*)take((size_t)N_GRAPHS * 4);
  if ((size_t)((char*)p - (char*)d_ws) > ws_size) return;

  // odeg and cur are adjacent: one memset covers both
  hipMemsetAsync(odeg, 0, (size_t)N_NODES * 4 * 2 + 256, stream);
  hipMemsetAsync(psum, 0, (size_t)N_GRAPHS * 32 * 4, stream);
  hipMemsetAsync(pcnt, 0, (size_t)N_GRAPHS * 4, stream);

  // ---- graph structure: single merged atomic pass, 4 edges/thread ----
  k_build<<<(E4 + 255) / 256, 256, 0, stream>>>(src, dst, odeg, cur, colp);
  k_rsqrt<<<(N_NODES + 255) / 256, 256, 0, stream>>>(odeg, cur, ascl, bscl);

  // ---- dtype prep (h pre-scaled by ascl) ----
  k_prep<<<(N_NODES * 128 + 255) / 256, 256, 0, stream>>>(h, ascl, hb);
  for (int i = 0; i < 6; ++i)
    k_wt<<<(FI[i] * FO[i] + 255) / 256, 256, 0, stream>>>(W[i], Wt[i], FI[i], FO[i]);

  const int GY = M_PAD / 128;   // 782
  const int GS = N_NODES / 4;   // 25000 — one node per wave, 4 waves/block

  // L1 (512->1024): agg first (pre-scaled input), then W + bias + relu
  k_spmm<512><<<GS, 256, 0, stream>>>(cur, colp, hb, bscl, nullptr, bufA, 0);
  k_mfma<128,128,64,64><<<8 * GY, 256, 0, stream>>>(bufA, Wt[0], b[0], nullptr, bufB, 1024, 512, 1);

  // L2 (1024->512): W first (rowscaled), then agg + bias + relu
  k_mfma<128,128,64,64><<<4 * GY, 256, 0, stream>>>(bufB, Wt[1], nullptr, ascl, bufA, 512, 1024, 2);
  k_spmm<512><<<GS, 256, 0, stream>>>(cur, colp, bufA, bscl, b[1], hb, 1);

  // L3 (512->256)
  k_mfma<128,128,64,64><<<2 * GY, 256, 0, stream>>>(hb, Wt[2], nullptr, ascl, bufA, 256, 512, 2);
  k_spmm<256><<<GS, 256, 0, stream>>>(cur, colp, bufA, bscl, b[2], hb, 1);

  // L4 (256->128)
  k_mfma<128,128,64,64><<<1 * GY, 256, 0, stream>>>(hb, Wt[3], nullptr, ascl, bufA, 128, 256, 2);
  k_spmm<128><<<GS, 256, 0, stream>>>(cur, colp, bufA, bscl, b[3], hb, 1);

  // L5 (128->64)
  k_mfma<128,64,64,32><<<1 * GY, 256, 0, stream>>>(hb, Wt[4], nullptr, ascl, bufA, 64, 128, 2);
  k_spmm<64><<<GS, 256, 0, stream>>>(cur, colp, bufA, bscl, b[4], hb, 1);

  // L6 (64->32)
  k_mfma<128,32,64,16><<<1 * GY, 256, 0, stream>>>(hb, Wt[5], nullptr, ascl, bufA, 32, 64, 2);
  k_spmm<32><<<GS, 256, 0, stream>>>(cur, colp, bufA, bscl, b[5], hb, 1);

  // mean-pool + classifier
  k_pool<<<(N_NODES + 255) / 256, 256, 0, stream>>>(hb, gid, psum, pcnt);
  k_final<<<1, 640, 0, stream>>>(psum, pcnt, Wc, bc, out);
}